// Round 6
// baseline (103872.290 us; speedup 1.0000x reference)
//
#include <hip/hip_runtime.h>
#include <math.h>

#define NB 128
#define DHH 512
#define MM 4096
#define DD 128
#define EPSV 1e-8f
#define NTILES 8192

typedef float f32x4 __attribute__((ext_vector_type(4)));

// d_out float offsets
#define HO_OFF 0
#define CN_OFF 65536
#define K_OFF  67174400
#define R_OFF  67190784

// d_ws float offsets (flags in first 1024 floats)
#define SBUF_F 1024
#define RACC_F (SBUF_F + 524288)
#define LMAX_F (RACC_F + 1048576)
#define LSUM_F (LMAX_F + 8192)
#define GH_F   (LSUM_F + 8192)
#define BRAW_F (GH_F + 196608)
#define EB_F   (BRAW_F + 128)
#define VB_F   (EB_F + 16384)
#define GZ_F   (VB_F + 16384)
// flags ints: [0]=abctr [1]=c_taken [2]=c_count [3]=c_batches [4..131]=done [132..259]=c_order

struct Seg { int jend; const float* W; const float* B; float* dst; int stride; int act; };

__device__ __forceinline__ float sigm(float x){ return 1.0f/(1.0f+expf(-x)); }

// Generic small-GEMM: out[n, j] = act( X[n,:K] . W[j,:K] + B[j] ), 8 j's per block.
template<int K>
__global__ __launch_bounds__(512) void proj8(const float* __restrict__ X, Seg s0, Seg s1, Seg s2)
{
    __shared__ float wlds[8][K];
    __shared__ float red[4][128][9];
    int t = threadIdx.x;
    int jbase = blockIdx.x * 8;
    for (int idx = t; idx < 8*K; idx += 512){
        int jj = idx / K, kk = idx - jj*K;
        int j = jbase + jj;
        const float* wrow = nullptr;
        if (j < s0.jend) wrow = s0.W + (size_t)j * K;
        else if (j < s1.jend) wrow = s1.W + (size_t)(j - s0.jend) * K;
        else if (j < s2.jend) wrow = s2.W + (size_t)(j - s1.jend) * K;
        wlds[jj][kk] = wrow ? wrow[kk] : 0.0f;
    }
    __syncthreads();
    {
        int n = t & 127, q = t >> 7;
        const int KQ = K/4;
        float acc[8];
        #pragma unroll
        for (int jj=0;jj<8;jj++) acc[jj]=0.0f;
        const float* xrow = X + (size_t)n*K + q*KQ;
        const float* wq = &wlds[0][0] + q*KQ;
        for (int kk=0; kk<KQ; ++kk){
            float xv = xrow[kk];
            #pragma unroll
            for (int jj=0;jj<8;jj++) acc[jj] = fmaf(xv, wq[jj*K+kk], acc[jj]);
        }
        #pragma unroll
        for (int jj=0;jj<8;jj++) red[q][n][jj] = acc[jj];
    }
    __syncthreads();
    if (t < 128){
        #pragma unroll
        for (int jj=0;jj<8;jj++){
            int j = jbase + jj;
            const Seg* sg = nullptr; int loc = 0;
            if (j < s0.jend){ sg=&s0; loc=j; }
            else if (j < s1.jend){ sg=&s1; loc=j-s0.jend; }
            else if (j < s2.jend){ sg=&s2; loc=j-s1.jend; }
            if (sg){
                float v = red[0][t][jj]+red[1][t][jj]+red[2][t][jj]+red[3][t][jj] + sg->B[loc];
                if (sg->act==1) v = sigm(v);
                sg->dst[(size_t)t * sg->stride + loc] = v;
            }
        }
    }
}

// Single persistent kernel: dynamic queue of 8192 AB tiles + 8192 C tiles.
// AB(n-major) -> last finisher of n runs mid(n) inline, enqueues C(n).
// Blocks prefer enqueued C work => C(n) re-read hits L3 (read ~10-20MB earlier).
__global__ __launch_bounds__(256, 2) void pipeline(
    const float* __restrict__ C, const float* __restrict__ kv,
    const float* __restrict__ braw, const float* __restrict__ gh,
    const float* __restrict__ hp,
    const float* __restrict__ W_ih, const float* __restrict__ b_ih,
    const float* __restrict__ We, const float* __restrict__ be,
    const float* __restrict__ Wv, const float* __restrict__ bv,
    float* __restrict__ sbuf, float* __restrict__ racc,
    float* __restrict__ lmaxb, float* __restrict__ lsumb,
    float* __restrict__ gz, float* __restrict__ ebuf, float* __restrict__ vbuf,
    float* __restrict__ r_out, float* __restrict__ ho,
    float* __restrict__ Cn, int* __restrict__ fl)
{
    __shared__ float rlds[4][128];
    __shared__ float wred[2][4];
    __shared__ __align__(16) float rsh[128];
    __shared__ float alpha[64];
    __shared__ float gish[1536];
    __shared__ __align__(16) float hosh[512];
    __shared__ float zsh;
    __shared__ int s_type, s_tk, s_flag;
    int tid = threadIdx.x;
    int* done    = fl + 4;
    int* c_order = fl + 132;

    while (true){
        if (tid == 0){
            int type = 0, tk = -1;
            // prefer enqueued C work (bounded CAS claim -> never over-claims)
            int cur = __hip_atomic_load(&fl[1], __ATOMIC_RELAXED, __HIP_MEMORY_SCOPE_AGENT);
            while (cur < __hip_atomic_load(&fl[2], __ATOMIC_ACQUIRE, __HIP_MEMORY_SCOPE_AGENT)){
                int old = atomicCAS(&fl[1], cur, cur+1);
                if (old == cur){ tk = cur; break; }
                cur = old;
            }
            if (tk >= 0) type = 2;
            else {
                int t = atomicAdd(&fl[0], 1);
                if (t < NTILES){ type = 1; tk = t; }
                else {
                    // drain: wait for C work or exhaustion (producers are live blocks)
                    while (true){
                        cur = __hip_atomic_load(&fl[1], __ATOMIC_RELAXED, __HIP_MEMORY_SCOPE_AGENT);
                        int cc = __hip_atomic_load(&fl[2], __ATOMIC_ACQUIRE, __HIP_MEMORY_SCOPE_AGENT);
                        if (cur < cc){
                            int old = atomicCAS(&fl[1], cur, cur+1);
                            if (old == cur){ tk = cur; type = 2; break; }
                        } else if (cur >= NTILES){ type = 0; break; }
                        else __builtin_amdgcn_s_sleep(8);
                    }
                }
            }
            s_type = type; s_tk = tk;
        }
        __syncthreads();
        int type = s_type, tk = s_tk;
        if (type == 0) break;

        if (type == 1){
            // ================= AB tile =================
            int n = tk >> 6, chunk = tk & 63, mbase = chunk << 6;
            int lane = tid & 63, w = tid >> 6;
            int s = tid & 15, rowg = tid >> 4;

            const float4* k4 = (const float4*)(kv + (size_t)n*DD);
            float4 ka = k4[s*2], kb = k4[s*2+1];
            float kq = ka.x*ka.x+ka.y*ka.y+ka.z*ka.z+ka.w*ka.w
                     + kb.x*kb.x+kb.y*kb.y+kb.z*kb.z+kb.w*kb.w;
            #pragma unroll
            for (int off=1; off<16; off<<=1) kq += __shfl_xor(kq, off);
            float knorm = sqrtf(kq);
            float b = braw[n];
            float beta = 1.0f + fmaxf(b, 0.0f) + log1pf(expf(-fabsf(b)));

            const float4* C4 = (const float4*)C;
            float4 av[4], bw[4];
            float sval[4];
            #pragma unroll
            for (int it=0; it<4; ++it){
                int m = mbase + it*16 + rowg;
                size_t ridx = ((size_t)n*MM + m)*32 + s*2;
                float4 a = C4[ridx], b4 = C4[ridx+1];
                av[it] = a; bw[it] = b4;
                float dot = a.x*ka.x + a.y*ka.y + a.z*ka.z + a.w*ka.w
                          + b4.x*kb.x + b4.y*kb.y + b4.z*kb.z + b4.w*kb.w;
                float nr  = a.x*a.x + a.y*a.y + a.z*a.z + a.w*a.w
                          + b4.x*b4.x + b4.y*b4.y + b4.z*b4.z + b4.w*b4.w;
                #pragma unroll
                for (int off=1; off<16; off<<=1){
                    dot += __shfl_xor(dot, off);
                    nr  += __shfl_xor(nr, off);
                }
                float sv = beta * dot / fmaxf(sqrtf(nr)*knorm, EPSV);
                sval[it] = sv;
                if (s == 0) sbuf[(size_t)n*MM + m] = sv;
            }
            float lm = fmaxf(fmaxf(sval[0],sval[1]), fmaxf(sval[2],sval[3]));
            lm = fmaxf(lm, __shfl_xor(lm, 16));
            lm = fmaxf(lm, __shfl_xor(lm, 32));
            if (lane == 0) wred[0][w] = lm;
            __syncthreads();
            float lmax = fmaxf(fmaxf(wred[0][0], wred[0][1]), fmaxf(wred[0][2], wred[0][3]));

            float r8[8] = {0,0,0,0,0,0,0,0};
            float ps = 0.0f;
            #pragma unroll
            for (int it=0; it<4; ++it){
                float p = expf(sval[it] - lmax);
                ps += p;
                r8[0] = fmaf(p, av[it].x, r8[0]); r8[1] = fmaf(p, av[it].y, r8[1]);
                r8[2] = fmaf(p, av[it].z, r8[2]); r8[3] = fmaf(p, av[it].w, r8[3]);
                r8[4] = fmaf(p, bw[it].x, r8[4]); r8[5] = fmaf(p, bw[it].y, r8[5]);
                r8[6] = fmaf(p, bw[it].z, r8[6]); r8[7] = fmaf(p, bw[it].w, r8[7]);
            }
            ps += __shfl_xor(ps, 16); ps += __shfl_xor(ps, 32);
            #pragma unroll
            for (int j=0;j<8;j++){
                r8[j] += __shfl_xor(r8[j], 16);
                r8[j] += __shfl_xor(r8[j], 32);
            }
            if (lane < 16){
                #pragma unroll
                for (int j=0;j<8;j++) rlds[w][lane*8+j] = r8[j];
            }
            if (lane == 0) wred[1][w] = ps;
            __syncthreads();
            if (tid < 128)
                racc[(size_t)tk*128 + tid] = rlds[0][tid]+rlds[1][tid]+rlds[2][tid]+rlds[3][tid];
            if (tid == 0){
                lmaxb[tk] = lmax;
                lsumb[tk] = wred[1][0]+wred[1][1]+wred[1][2]+wred[1][3];
            }
            __syncthreads();   // all global writes drained (syncthreads waits vmcnt)
            if (tid == 0){
                __threadfence();                    // release tile data (wb L2)
                int ret = atomicAdd(&done[n], 1);
                int last = (ret == 63);
                if (last) __threadfence();          // acquire peers' data (inv)
                s_flag = last;
            }
            __syncthreads();
            if (s_flag){
                // ============ mid(n): combine -> r; gi; GRU; e,v ============
                if (tid < 64){
                    float lmv = lmaxb[n*64 + tid];
                    float gm = lmv;
                    #pragma unroll
                    for (int off=1; off<64; off<<=1) gm = fmaxf(gm, __shfl_xor(gm, off));
                    float a = expf(lmv - gm);
                    alpha[tid] = a;
                    float zc = a * lsumb[n*64 + tid];
                    #pragma unroll
                    for (int off=1; off<64; off<<=1) zc += __shfl_xor(zc, off);
                    if (tid == 0){ zsh = zc; gz[n] = gm; gz[128+n] = 1.0f/zc; }
                }
                __syncthreads();
                float invZ = 1.0f / zsh;
                if (tid < 128){
                    const float* rb = racc + (size_t)n*64*128 + tid;
                    float acc = 0.0f;
                    #pragma unroll 8
                    for (int c=0; c<64; c++) acc = fmaf(alpha[c], rb[c*128], acc);
                    float rv = acc * invZ;
                    rsh[tid] = rv;
                    r_out[n*DD + tid] = rv;
                }
                __syncthreads();
                {
                    const float4* r4 = (const float4*)rsh;
                    #pragma unroll
                    for (int u=0; u<6; u++){
                        int j = tid + 256*u;
                        const float4* wr = (const float4*)(W_ih + (size_t)j*DD);
                        float acc = b_ih[j];
                        #pragma unroll 8
                        for (int kk=0; kk<32; kk++){
                            float4 ww = wr[kk], rr = r4[kk];
                            acc = fmaf(ww.x, rr.x, fmaf(ww.y, rr.y, fmaf(ww.z, rr.z, fmaf(ww.w, rr.w, acc))));
                        }
                        gish[j] = acc;
                    }
                }
                __syncthreads();
                {
                    const float* ghr = gh + (size_t)n*1536;
                    #pragma unroll
                    for (int u=0; u<2; u++){
                        int j = tid + 256*u;
                        float rg = sigm(gish[j] + ghr[j]);
                        float z  = sigm(gish[512+j] + ghr[512+j]);
                        float ng = tanhf(gish[1024+j] + rg*ghr[1024+j]);
                        float h  = hp[(size_t)n*DHH + j];
                        float hv = (1.0f - z)*ng + z*h;
                        hosh[j] = hv;
                        ho[(size_t)n*DHH + j] = hv;
                    }
                }
                __syncthreads();
                {
                    const float* Wrow = (tid < 128) ? (We + (size_t)tid*DHH) : (Wv + (size_t)(tid-128)*DHH);
                    float acc = (tid < 128) ? be[tid] : bv[tid-128];
                    const float4* w4 = (const float4*)Wrow;
                    const float4* h4 = (const float4*)hosh;
                    #pragma unroll 8
                    for (int kk=0; kk<128; kk++){
                        float4 ww = w4[kk], hh = h4[kk];
                        acc = fmaf(ww.x, hh.x, fmaf(ww.y, hh.y, fmaf(ww.z, hh.z, fmaf(ww.w, hh.w, acc))));
                    }
                    if (tid < 128) ebuf[n*DD + tid] = sigm(acc);
                    else           vbuf[n*DD + (tid-128)] = acc;
                }
                __syncthreads();   // e/v stores drained
                if (tid == 0){
                    int pos = atomicAdd(&fl[3], 1);
                    c_order[pos] = n;
                    __threadfence();               // release mid data + c_order
                    atomicAdd(&fl[2], 64);         // enqueue 64 C tiles
                }
            }
        } else {
            // ================= C tile =================
            int batch = tk >> 6, chunk = tk & 63, mbase = chunk << 6;
            if (tid == 0) s_flag = c_order[batch];  // valid: claim acquired c_count
            __syncthreads();
            int n = s_flag;
            if (tid < 64){
                float gm = gz[n], iz = gz[128+n];
                alpha[tid] = expf(sbuf[(size_t)n*MM + mbase + tid] - gm) * iz;
            }
            __syncthreads();
            int l = tid & 31, q = tid >> 5;
            f32x4 e4 = ((const f32x4*)(ebuf + (size_t)n*DD))[l];
            f32x4 v4 = ((const f32x4*)(vbuf + (size_t)n*DD))[l];
            const f32x4* C4 = (const f32x4*)C;
            f32x4* Cn4 = (f32x4*)Cn;
            #pragma unroll
            for (int it=0; it<8; ++it){
                int m = mbase + it*8 + q;
                float wm = alpha[it*8 + q];
                size_t ridx = ((size_t)n*MM + m)*32 + l;
                f32x4 c = C4[ridx];
                f32x4 o;
                o.x = fmaf(wm, v4.x, c.x * (1.0f - wm*e4.x));
                o.y = fmaf(wm, v4.y, c.y * (1.0f - wm*e4.y));
                o.z = fmaf(wm, v4.z, c.z * (1.0f - wm*e4.z));
                o.w = fmaf(wm, v4.w, c.w * (1.0f - wm*e4.w));
                __builtin_nontemporal_store(o, &Cn4[ridx]);
            }
        }
        __syncthreads();
    }
}

extern "C" void kernel_launch(void* const* d_in, const int* in_sizes, int n_in,
                              void* d_out, int out_size, void* d_ws, size_t ws_size,
                              hipStream_t stream) {
    const float* hp   = (const float*)d_in[0];
    const float* C    = (const float*)d_in[1];
    const float* Wk   = (const float*)d_in[2];
    const float* bk   = (const float*)d_in[3];
    const float* Wb   = (const float*)d_in[4];
    const float* bb   = (const float*)d_in[5];
    const float* We   = (const float*)d_in[6];
    const float* be   = (const float*)d_in[7];
    const float* Wv   = (const float*)d_in[8];
    const float* bv   = (const float*)d_in[9];
    const float* W_ih = (const float*)d_in[10];
    const float* b_ih = (const float*)d_in[11];
    const float* W_hh = (const float*)d_in[12];
    const float* b_hh = (const float*)d_in[13];

    float* out   = (float*)d_out;
    float* ho    = out + HO_OFF;
    float* Cn    = out + CN_OFF;
    float* k_out = out + K_OFF;
    float* r_out = out + R_OFF;

    float* wsf   = (float*)d_ws;
    int*   fl    = (int*)d_ws;
    float* sbuf  = wsf + SBUF_F;
    float* racc  = wsf + RACC_F;
    float* lmaxb = wsf + LMAX_F;
    float* lsumb = wsf + LSUM_F;
    float* gh    = wsf + GH_F;
    float* braw  = wsf + BRAW_F;
    float* ebuf  = wsf + EB_F;
    float* vbuf  = wsf + VB_F;
    float* gz    = wsf + GZ_F;

    // 0) zero queue state (captured; re-zeroed every replay)
    hipMemsetAsync(d_ws, 0, 4096, stream);

    // 1) k, gh, beta_pre (from h_o_prev, K=512)
    {
        Seg s0 = {128, Wk, bk, k_out, 128, 0};
        Seg s1 = {1664, W_hh, b_hh, gh, 1536, 0};
        Seg s2 = {1665, Wb, bb, braw, 1, 0};
        proj8<512><<<209, 512, 0, stream>>>(hp, s0, s1, s2);
    }

    // 2) persistent pipelined AB -> mid -> C kernel, grid sized to co-residency
    int dev = 0;
    hipGetDevice(&dev);
    hipDeviceProp_t prop;
    hipGetDeviceProperties(&prop, dev);
    int maxb = 0;
    hipOccupancyMaxActiveBlocksPerMultiprocessor(&maxb, pipeline, 256, 0);
    if (maxb < 1) maxb = 1;
    long grid = (long)prop.multiProcessorCount * maxb;
    if (grid > 2048) grid = 2048;
    if (grid < 64) grid = 64;

    pipeline<<<(int)grid, 256, 0, stream>>>(C, k_out, braw, gh, hp,
                                            W_ih, b_ih, We, be, Wv, bv,
                                            sbuf, racc, lmaxb, lsumb,
                                            gz, ebuf, vbuf, r_out, ho, Cn, fl);
}

// Round 7
// 553.584 us; speedup vs baseline: 187.6360x; 187.6360x over previous
//
#include <hip/hip_runtime.h>
#include <hip/hip_cooperative_groups.h>
#include <math.h>

namespace cg = cooperative_groups;

#define NB 128
#define DHH 512
#define MM 4096
#define DD 128
#define EPSV 1e-8f
#define NTILES 8192

typedef float f32x4 __attribute__((ext_vector_type(4)));

// d_out float offsets
#define HO_OFF 0
#define CN_OFF 65536
#define K_OFF  67174400
#define R_OFF  67190784

// d_ws float offsets
#define SBUF_F 1024
#define RACC_F (SBUF_F + 524288)
#define LMAX_F (RACC_F + 1048576)
#define LSUM_F (LMAX_F + 8192)
#define GH_F   (LSUM_F + 8192)
#define BRAW_F (GH_F + 196608)
#define EB_F   (BRAW_F + 128)
#define VB_F   (EB_F + 16384)
#define GZ_F   (VB_F + 16384)

struct Seg { int jend; const float* W; const float* B; float* dst; int stride; int act; };

__device__ __forceinline__ float sigm(float x){ return 1.0f/(1.0f+expf(-x)); }

// Generic small-GEMM: out[n, j] = act( X[n,:K] . W[j,:K] + B[j] ), 8 j's per block.
template<int K>
__global__ __launch_bounds__(512) void proj8(const float* __restrict__ X, Seg s0, Seg s1, Seg s2)
{
    __shared__ float wlds[8][K];
    __shared__ float red[4][128][9];
    int t = threadIdx.x;
    int jbase = blockIdx.x * 8;
    for (int idx = t; idx < 8*K; idx += 512){
        int jj = idx / K, kk = idx - jj*K;
        int j = jbase + jj;
        const float* wrow = nullptr;
        if (j < s0.jend) wrow = s0.W + (size_t)j * K;
        else if (j < s1.jend) wrow = s1.W + (size_t)(j - s0.jend) * K;
        else if (j < s2.jend) wrow = s2.W + (size_t)(j - s1.jend) * K;
        wlds[jj][kk] = wrow ? wrow[kk] : 0.0f;
    }
    __syncthreads();
    {
        int n = t & 127, q = t >> 7;
        const int KQ = K/4;
        float acc[8];
        #pragma unroll
        for (int jj=0;jj<8;jj++) acc[jj]=0.0f;
        const float* xrow = X + (size_t)n*K + q*KQ;
        const float* wq = &wlds[0][0] + q*KQ;
        for (int kk=0; kk<KQ; ++kk){
            float xv = xrow[kk];
            #pragma unroll
            for (int jj=0;jj<8;jj++) acc[jj] = fmaf(xv, wq[jj*K+kk], acc[jj]);
        }
        #pragma unroll
        for (int jj=0;jj<8;jj++) red[q][n][jj] = acc[jj];
    }
    __syncthreads();
    if (t < 128){
        #pragma unroll
        for (int jj=0;jj<8;jj++){
            int j = jbase + jj;
            const Seg* sg = nullptr; int loc = 0;
            if (j < s0.jend){ sg=&s0; loc=j; }
            else if (j < s1.jend){ sg=&s1; loc=j-s0.jend; }
            else if (j < s2.jend){ sg=&s2; loc=j-s1.jend; }
            if (sg){
                float v = red[0][t][jj]+red[1][t][jj]+red[2][t][jj]+red[3][t][jj] + sg->B[loc];
                if (sg->act==1) v = sigm(v);
                sg->dst[(size_t)t * sg->stride + loc] = v;
            }
        }
    }
}

struct CoopArgs {
    const float *C, *kv, *braw, *gh, *hp;
    const float *W_ih, *b_ih, *We, *be, *Wv, *bv;
    float *sbuf, *racc, *lmaxb, *lsumb, *gz, *ebuf, *vbuf, *r_out, *ho, *Cn;
};

// Fused AB -> mid -> C with grid-wide syncs. Strided tile mapping (t = r*G + b);
// C phase walks rounds in reverse so most-recently-read C tiles are re-read first (L2/L3 hot).
__global__ __launch_bounds__(256) void fused(CoopArgs a)
{
    cg::grid_group grid = cg::this_grid();
    __shared__ float rlds[4][128];
    __shared__ float wred[2][4];
    __shared__ __align__(16) float rsh[128];
    __shared__ float alpha[64];
    __shared__ float gish[1536];
    __shared__ __align__(16) float hosh[512];
    __shared__ float zsh;

    int G = gridDim.x, b = blockIdx.x, tid = threadIdx.x;
    int rounds = (NTILES + G - 1) / G;
    int lane = tid & 63, w = tid >> 6;
    int s = tid & 15, rowg = tid >> 4;

    // ================= phase AB =================
    for (int rIt = 0; rIt < rounds; ++rIt){
        int tk = rIt*G + b;
        if (tk < NTILES){
            int n = tk >> 6, chunk = tk & 63, mbase = chunk << 6;

            const float4* k4 = (const float4*)(a.kv + (size_t)n*DD);
            float4 ka = k4[s*2], kb = k4[s*2+1];
            float kq = ka.x*ka.x+ka.y*ka.y+ka.z*ka.z+ka.w*ka.w
                     + kb.x*kb.x+kb.y*kb.y+kb.z*kb.z+kb.w*kb.w;
            #pragma unroll
            for (int off=1; off<16; off<<=1) kq += __shfl_xor(kq, off);
            float knorm = sqrtf(kq);
            float bb_ = a.braw[n];
            float beta = 1.0f + fmaxf(bb_, 0.0f) + log1pf(expf(-fabsf(bb_)));

            const float4* C4 = (const float4*)a.C;
            float4 av[4], bw[4];
            float sval[4];
            #pragma unroll
            for (int it=0; it<4; ++it){
                int m = mbase + it*16 + rowg;
                size_t ridx = ((size_t)n*MM + m)*32 + s*2;
                float4 a4 = C4[ridx], b4 = C4[ridx+1];
                av[it] = a4; bw[it] = b4;
                float dot = a4.x*ka.x + a4.y*ka.y + a4.z*ka.z + a4.w*ka.w
                          + b4.x*kb.x + b4.y*kb.y + b4.z*kb.z + b4.w*kb.w;
                float nr  = a4.x*a4.x + a4.y*a4.y + a4.z*a4.z + a4.w*a4.w
                          + b4.x*b4.x + b4.y*b4.y + b4.z*b4.z + b4.w*b4.w;
                #pragma unroll
                for (int off=1; off<16; off<<=1){
                    dot += __shfl_xor(dot, off);
                    nr  += __shfl_xor(nr, off);
                }
                float sv = beta * dot / fmaxf(sqrtf(nr)*knorm, EPSV);
                sval[it] = sv;
                if (s == 0) a.sbuf[(size_t)n*MM + m] = sv;
            }
            float lm = fmaxf(fmaxf(sval[0],sval[1]), fmaxf(sval[2],sval[3]));
            lm = fmaxf(lm, __shfl_xor(lm, 16));
            lm = fmaxf(lm, __shfl_xor(lm, 32));
            if (lane == 0) wred[0][w] = lm;
            __syncthreads();
            float lmax = fmaxf(fmaxf(wred[0][0], wred[0][1]), fmaxf(wred[0][2], wred[0][3]));

            float r8[8] = {0,0,0,0,0,0,0,0};
            float ps = 0.0f;
            #pragma unroll
            for (int it=0; it<4; ++it){
                float p = expf(sval[it] - lmax);
                ps += p;
                r8[0] = fmaf(p, av[it].x, r8[0]); r8[1] = fmaf(p, av[it].y, r8[1]);
                r8[2] = fmaf(p, av[it].z, r8[2]); r8[3] = fmaf(p, av[it].w, r8[3]);
                r8[4] = fmaf(p, bw[it].x, r8[4]); r8[5] = fmaf(p, bw[it].y, r8[5]);
                r8[6] = fmaf(p, bw[it].z, r8[6]); r8[7] = fmaf(p, bw[it].w, r8[7]);
            }
            ps += __shfl_xor(ps, 16); ps += __shfl_xor(ps, 32);
            #pragma unroll
            for (int j=0;j<8;j++){
                r8[j] += __shfl_xor(r8[j], 16);
                r8[j] += __shfl_xor(r8[j], 32);
            }
            if (lane < 16){
                #pragma unroll
                for (int j=0;j<8;j++) rlds[w][lane*8+j] = r8[j];
            }
            if (lane == 0) wred[1][w] = ps;
            __syncthreads();
            if (tid < 128)
                a.racc[(size_t)tk*128 + tid] = rlds[0][tid]+rlds[1][tid]+rlds[2][tid]+rlds[3][tid];
            if (tid == 0){
                a.lmaxb[tk] = lmax;
                a.lsumb[tk] = wred[1][0]+wred[1][1]+wred[1][2]+wred[1][3];
            }
            __syncthreads();
        }
    }
    __threadfence();
    grid.sync();

    // ================= phase mid (blocks 0..127) =================
    if (b < NB){
        int n = b;
        if (tid < 64){
            float lmv = a.lmaxb[n*64 + tid];
            float gm = lmv;
            #pragma unroll
            for (int off=1; off<64; off<<=1) gm = fmaxf(gm, __shfl_xor(gm, off));
            float al = expf(lmv - gm);
            alpha[tid] = al;
            float zc = al * a.lsumb[n*64 + tid];
            #pragma unroll
            for (int off=1; off<64; off<<=1) zc += __shfl_xor(zc, off);
            if (tid == 0){ zsh = zc; a.gz[n] = gm; a.gz[128+n] = 1.0f/zc; }
        }
        __syncthreads();
        float invZ = 1.0f / zsh;
        if (tid < 128){
            const float* rb = a.racc + (size_t)n*64*128 + tid;
            float acc = 0.0f;
            #pragma unroll 8
            for (int c=0; c<64; c++) acc = fmaf(alpha[c], rb[c*128], acc);
            float rv = acc * invZ;
            rsh[tid] = rv;
            a.r_out[n*DD + tid] = rv;
        }
        __syncthreads();
        {
            const float4* r4 = (const float4*)rsh;
            #pragma unroll
            for (int u=0; u<6; u++){
                int j = tid + 256*u;
                const float4* wr = (const float4*)(a.W_ih + (size_t)j*DD);
                float acc = a.b_ih[j];
                #pragma unroll 8
                for (int kk=0; kk<32; kk++){
                    float4 ww = wr[kk], rr = r4[kk];
                    acc = fmaf(ww.x, rr.x, fmaf(ww.y, rr.y, fmaf(ww.z, rr.z, fmaf(ww.w, rr.w, acc))));
                }
                gish[j] = acc;
            }
        }
        __syncthreads();
        {
            const float* ghr = a.gh + (size_t)n*1536;
            #pragma unroll
            for (int u=0; u<2; u++){
                int j = tid + 256*u;
                float rg = sigm(gish[j] + ghr[j]);
                float z  = sigm(gish[512+j] + ghr[512+j]);
                float ng = tanhf(gish[1024+j] + rg*ghr[1024+j]);
                float h  = a.hp[(size_t)n*DHH + j];
                float hv = (1.0f - z)*ng + z*h;
                hosh[j] = hv;
                a.ho[(size_t)n*DHH + j] = hv;
            }
        }
        __syncthreads();
        {
            const float* Wrow = (tid < 128) ? (a.We + (size_t)tid*DHH) : (a.Wv + (size_t)(tid-128)*DHH);
            float acc = (tid < 128) ? a.be[tid] : a.bv[tid-128];
            const float4* w4 = (const float4*)Wrow;
            const float4* h4 = (const float4*)hosh;
            #pragma unroll 8
            for (int kk=0; kk<128; kk++){
                float4 ww = w4[kk], hh = h4[kk];
                acc = fmaf(ww.x, hh.x, fmaf(ww.y, hh.y, fmaf(ww.z, hh.z, fmaf(ww.w, hh.w, acc))));
            }
            if (tid < 128) a.ebuf[n*DD + tid] = sigm(acc);
            else           a.vbuf[n*DD + (tid-128)] = acc;
        }
    }
    __threadfence();
    grid.sync();

    // ================= phase C (rounds reversed: hottest tiles first) =================
    for (int rIt = rounds-1; rIt >= 0; --rIt){
        int tk = rIt*G + b;
        if (tk < NTILES){
            int n = tk >> 6, mbase = (tk & 63) << 6;
            if (tid < 64){
                float gm = a.gz[n], iz = a.gz[128+n];
                alpha[tid] = expf(a.sbuf[(size_t)n*MM + mbase + tid] - gm) * iz;
            }
            __syncthreads();
            int l = tid & 31, q = tid >> 5;
            f32x4 e4 = ((const f32x4*)(a.ebuf + (size_t)n*DD))[l];
            f32x4 v4 = ((const f32x4*)(a.vbuf + (size_t)n*DD))[l];
            const f32x4* C4 = (const f32x4*)a.C;
            f32x4* Cn4 = (f32x4*)a.Cn;
            #pragma unroll
            for (int it=0; it<8; ++it){
                int m = mbase + it*8 + q;
                float wm = alpha[it*8 + q];
                size_t ridx = ((size_t)n*MM + m)*32 + l;
                f32x4 c = C4[ridx];
                f32x4 o;
                o.x = fmaf(wm, v4.x, c.x * (1.0f - wm*e4.x));
                o.y = fmaf(wm, v4.y, c.y * (1.0f - wm*e4.y));
                o.z = fmaf(wm, v4.z, c.z * (1.0f - wm*e4.z));
                o.w = fmaf(wm, v4.w, c.w * (1.0f - wm*e4.w));
                __builtin_nontemporal_store(o, &Cn4[ridx]);
            }
            __syncthreads();
        }
    }
}

extern "C" void kernel_launch(void* const* d_in, const int* in_sizes, int n_in,
                              void* d_out, int out_size, void* d_ws, size_t ws_size,
                              hipStream_t stream) {
    const float* hp   = (const float*)d_in[0];
    const float* C    = (const float*)d_in[1];
    const float* Wk   = (const float*)d_in[2];
    const float* bk   = (const float*)d_in[3];
    const float* Wb   = (const float*)d_in[4];
    const float* bb   = (const float*)d_in[5];
    const float* We   = (const float*)d_in[6];
    const float* be   = (const float*)d_in[7];
    const float* Wv   = (const float*)d_in[8];
    const float* bv   = (const float*)d_in[9];
    const float* W_ih = (const float*)d_in[10];
    const float* b_ih = (const float*)d_in[11];
    const float* W_hh = (const float*)d_in[12];
    const float* b_hh = (const float*)d_in[13];

    float* out   = (float*)d_out;
    float* ho    = out + HO_OFF;
    float* Cn    = out + CN_OFF;
    float* k_out = out + K_OFF;
    float* r_out = out + R_OFF;

    float* wsf   = (float*)d_ws;
    float* sbuf  = wsf + SBUF_F;
    float* racc  = wsf + RACC_F;
    float* lmaxb = wsf + LMAX_F;
    float* lsumb = wsf + LSUM_F;
    float* gh    = wsf + GH_F;
    float* braw  = wsf + BRAW_F;
    float* ebuf  = wsf + EB_F;
    float* vbuf  = wsf + VB_F;
    float* gz    = wsf + GZ_F;

    // 1) k, gh, beta_pre (from h_o_prev, K=512)
    {
        Seg s0 = {128, Wk, bk, k_out, 128, 0};
        Seg s1 = {1664, W_hh, b_hh, gh, 1536, 0};
        Seg s2 = {1665, Wb, bb, braw, 1, 0};
        proj8<512><<<209, 512, 0, stream>>>(hp, s0, s1, s2);
    }

    // 2) fused AB -> mid -> C cooperative kernel, grid = full co-residency
    int dev = 0;
    hipGetDevice(&dev);
    hipDeviceProp_t prop;
    hipGetDeviceProperties(&prop, dev);
    int maxb = 0;
    hipOccupancyMaxActiveBlocksPerMultiprocessor(&maxb, fused, 256, 0);
    if (maxb < 1) maxb = 1;
    long grid = (long)prop.multiProcessorCount * maxb;
    if (grid > NTILES) grid = NTILES;
    if (grid < NB) grid = NB;

    CoopArgs args = { C, k_out, braw, gh, hp,
                      W_ih, b_ih, We, be, Wv, bv,
                      sbuf, racc, lmaxb, lsumb, gz, ebuf, vbuf,
                      r_out, ho, Cn };
    void* kargs[] = { &args };
    hipLaunchCooperativeKernel((const void*)fused, dim3((int)grid), dim3(256),
                               kargs, 0, stream);
}